// Round 2
// baseline (948.993 us; speedup 1.0000x reference)
//
#include <hip/hip_runtime.h>
#include <hip/hip_bf16.h>

// GNN: 2-layer GraphConv (DGL norm='both'), N=100000 nodes, E=1600000 edges.
// Layer1: 128->64 + relu, Layer2: 64->32.
// out = (segsum(h[src] -> dst) * in_norm + b), h = (x*out_norm)@W

#define NN 100000

// ---------------- degree count (edge atomics) ----------------
__global__ void k_degree(const int* __restrict__ src, const int* __restrict__ dst,
                         float* __restrict__ degO, float* __restrict__ degI, int E) {
    int i = blockIdx.x * blockDim.x + threadIdx.x;
    if (i < E) {
        atomicAdd(&degO[src[i]], 1.0f);
        atomicAdd(&degI[dst[i]], 1.0f);
    }
}

// deg -> rsqrt(max(deg,1)) in place
__global__ void k_norm(float* __restrict__ degO, float* __restrict__ degI, int n) {
    int i = blockIdx.x * blockDim.x + threadIdx.x;
    if (i < n) {
        degO[i] = rsqrtf(fmaxf(degO[i], 1.0f));
        degI[i] = rsqrtf(fmaxf(degI[i], 1.0f));
    }
}

// ---------------- GEMM1: h1[row,col] = (x[row,:]*normO[row]) @ W1[:,col] ----------------
// block = 1024 threads = 16 rows x 64 cols. W1 (128x64) staged in LDS (32 KB).
__global__ void k_gemm1(const float* __restrict__ x, const float* __restrict__ W1,
                        const float* __restrict__ normO, float* __restrict__ h1, int n) {
    __shared__ float sW[128 * 64];
    for (int i = threadIdx.x; i < 128 * 64; i += blockDim.x) sW[i] = W1[i];
    __syncthreads();
    int col = threadIdx.x & 63;
    int row = blockIdx.x * 16 + (threadIdx.x >> 6);
    if (row >= n) return;
    const float4* xr4 = (const float4*)(x + (size_t)row * 128);
    float acc = 0.f;
#pragma unroll
    for (int k4 = 0; k4 < 32; k4++) {
        float4 xv = xr4[k4];
        int kb = k4 * 4;
        acc = fmaf(xv.x, sW[(kb + 0) * 64 + col], acc);
        acc = fmaf(xv.y, sW[(kb + 1) * 64 + col], acc);
        acc = fmaf(xv.z, sW[(kb + 2) * 64 + col], acc);
        acc = fmaf(xv.w, sW[(kb + 3) * 64 + col], acc);
    }
    h1[(size_t)row * 64 + col] = acc * normO[row];
}

// ---------------- scatter-add, 64 cols: one wave per edge ----------------
__global__ void k_scatter64(const float* __restrict__ h, const int* __restrict__ src,
                            const int* __restrict__ dst, float* __restrict__ agg, int E) {
    size_t gid = (size_t)blockIdx.x * blockDim.x + threadIdx.x;
    int e = (int)(gid >> 6);
    int col = (int)(gid & 63);
    if (e < E) {
        int s = src[e], d = dst[e];
        atomicAdd(&agg[(size_t)d * 64 + col], h[(size_t)s * 64 + col]);
    }
}

// ---------------- GEMM2 (fused relu+norms): 64->32 ----------------
// x2 = relu(agg1*normI + b1); h2 = (x2*normO) @ W2
// block = 1024 threads = 32 rows x 32 cols. W2 (64x32 = 8KB) + b1 in LDS.
__global__ void k_gemm2(const float* __restrict__ agg1, const float* __restrict__ W2,
                        const float* __restrict__ b1, const float* __restrict__ normI,
                        const float* __restrict__ normO, float* __restrict__ h2, int n) {
    __shared__ float sW[64 * 32];
    __shared__ float sb[64];
    for (int i = threadIdx.x; i < 64 * 32; i += blockDim.x) sW[i] = W2[i];
    if (threadIdx.x < 64) sb[threadIdx.x] = b1[threadIdx.x];
    __syncthreads();
    int col = threadIdx.x & 31;
    int row = blockIdx.x * 32 + (threadIdx.x >> 5);
    if (row >= n) return;
    float ni = normI[row], no = normO[row];
    const float* ar = agg1 + (size_t)row * 64;
    float acc = 0.f;
#pragma unroll
    for (int c = 0; c < 64; c++) {
        float v = fmaxf(fmaf(ar[c], ni, sb[c]), 0.f) * no;
        acc = fmaf(v, sW[c * 32 + col], acc);
    }
    h2[(size_t)row * 32 + col] = acc;
}

// ---------------- scatter-add, 32 cols: half wave per edge ----------------
__global__ void k_scatter32(const float* __restrict__ h, const int* __restrict__ src,
                            const int* __restrict__ dst, float* __restrict__ agg, int E) {
    size_t gid = (size_t)blockIdx.x * blockDim.x + threadIdx.x;
    int e = (int)(gid >> 5);
    int col = (int)(gid & 31);
    if (e < E) {
        int s = src[e], d = dst[e];
        atomicAdd(&agg[(size_t)d * 32 + col], h[(size_t)s * 32 + col]);
    }
}

// ---------------- final: out = out*normI + b2 (in place after scatter) ----------------
__global__ void k_final(float* __restrict__ out, const float* __restrict__ normI,
                        const float* __restrict__ b2, int n) {
    int gid = blockIdx.x * blockDim.x + threadIdx.x;
    int row = gid >> 5, col = gid & 31;
    if (row < n) out[gid] = out[gid] * normI[row] + b2[col];
}

extern "C" void kernel_launch(void* const* d_in, const int* in_sizes, int n_in,
                              void* d_out, int out_size, void* d_ws, size_t ws_size,
                              hipStream_t stream) {
    const float* x  = (const float*)d_in[0];   // [N,128]
    const int*   src = (const int*)d_in[1];    // [E]
    const int*   dst = (const int*)d_in[2];    // [E]
    const float* W1 = (const float*)d_in[3];   // [128,64]
    const float* b1 = (const float*)d_in[4];   // [64]
    const float* W2 = (const float*)d_in[5];   // [64,32]
    const float* b2 = (const float*)d_in[6];   // [32]
    float* out = (float*)d_out;                // [N,32]

    const int N = in_sizes[0] / 128;           // 100000
    const int E = in_sizes[1];                 // 1600000

    float* ws   = (float*)d_ws;
    float* degO = ws;                          // N   (becomes norm_out)
    float* degI = ws + N;                      // N   (becomes norm_in)
    float* h1   = ws + 2 * (size_t)N;          // N*64 (reused as h2: N*32)
    float* agg1 = h1 + (size_t)N * 64;         // N*64
    float* h2   = h1;                          // alias: h1 dead after scatter1

    // zero accumulators (d_out/d_ws are poisoned to 0xAA before every call)
    hipMemsetAsync(degO, 0, (size_t)N * sizeof(float), stream);
    hipMemsetAsync(degI, 0, (size_t)N * sizeof(float), stream);
    hipMemsetAsync(agg1, 0, (size_t)N * 64 * sizeof(float), stream);
    hipMemsetAsync(out,  0, (size_t)N * 32 * sizeof(float), stream);

    // degrees + norms
    k_degree<<<(E + 255) / 256, 256, 0, stream>>>(src, dst, degO, degI, E);
    k_norm<<<(N + 255) / 256, 256, 0, stream>>>(degO, degI, N);

    // layer 1
    k_gemm1<<<(N + 15) / 16, 1024, 0, stream>>>(x, W1, degO, h1, N);
    {
        size_t tot = (size_t)E * 64;
        k_scatter64<<<(unsigned)((tot + 255) / 256), 256, 0, stream>>>(h1, src, dst, agg1, E);
    }

    // layer 2 (relu + in_norm + b1 + out_norm fused into GEMM2 read)
    k_gemm2<<<(N + 31) / 32, 1024, 0, stream>>>(agg1, W2, b1, degI, degO, h2, N);
    {
        size_t tot = (size_t)E * 32;
        k_scatter32<<<(unsigned)((tot + 255) / 256), 256, 0, stream>>>(h2, src, dst, out, E);
    }

    // epilogue: out = agg2 * in_norm + b2
    k_final<<<(N * 32 + 255) / 256, 256, 0, stream>>>(out, degI, b2, N);
}

// Round 3
// 632.733 us; speedup vs baseline: 1.4998x; 1.4998x over previous
//
#include <hip/hip_runtime.h>
#include <hip/hip_bf16.h>

// GNN: 2-layer GraphConv (DGL norm='both'), N=100000, E=1600000.
// Round 3: atomic scatter-add replaced by on-device CSR build (counting sort
// by dst) + gather-based aggregation (one wave per destination node).
// Fusions: relu+b1+in_norm folded into agg1; out = agg2*in_norm+b2 folded
// into agg2 (no k_final, no big memsets).

// ---------------- degree count (int atomics) ----------------
__global__ void k_degree(const int* __restrict__ src, const int* __restrict__ dst,
                         int* __restrict__ dO, int* __restrict__ dI, int E) {
    int i = blockIdx.x * blockDim.x + threadIdx.x;
    if (i < E) {
        atomicAdd(&dO[src[i]], 1);
        atomicAdd(&dI[dst[i]], 1);
    }
}

// norms from int degrees
__global__ void k_norm(const int* __restrict__ dO, const int* __restrict__ dI,
                       float* __restrict__ nO, float* __restrict__ nI, int n) {
    int i = blockIdx.x * blockDim.x + threadIdx.x;
    if (i < n) {
        nO[i] = rsqrtf(fmaxf((float)dO[i], 1.0f));
        nI[i] = rsqrtf(fmaxf((float)dI[i], 1.0f));
    }
}

// ---------------- hierarchical exclusive scan of dI -> off ----------------
// A: per-1024 chunk Hillis-Steele, write local exclusive scan + chunk total
__global__ void k_scan_a(const int* __restrict__ deg, int* __restrict__ off,
                         int* __restrict__ partial, int n) {
    __shared__ int tmp[1024];
    int t = threadIdx.x;
    int i = blockIdx.x * 1024 + t;
    int v = (i < n) ? deg[i] : 0;
    tmp[t] = v;
    __syncthreads();
    for (int o = 1; o < 1024; o <<= 1) {
        int u = (t >= o) ? tmp[t - o] : 0;
        __syncthreads();
        tmp[t] += u;
        __syncthreads();
    }
    if (i < n) off[i] = tmp[t] - v;          // exclusive
    if (t == 1023) partial[blockIdx.x] = tmp[t];
}

// B: scan the (<=1024) chunk totals in one block
__global__ void k_scan_b(int* __restrict__ partial, int B) {
    __shared__ int s[1024];
    int t = threadIdx.x;
    for (int i = t; i < B; i += blockDim.x) s[i] = partial[i];
    __syncthreads();
    if (t == 0) {
        int acc = 0;
        for (int i = 0; i < B; i++) { int v = s[i]; s[i] = acc; acc += v; }
    }
    __syncthreads();
    for (int i = t; i < B; i += blockDim.x) partial[i] = s[i];
}

// C: add chunk base
__global__ void k_scan_c(int* __restrict__ off, const int* __restrict__ partial, int n) {
    int i = blockIdx.x * 1024 + threadIdx.x;
    if (i < n) off[i] += partial[blockIdx.x];
}

// ---------------- CSR fill: off[d] advances from start(d) to end(d) ----------------
// After this kernel: off[d] == end(d) == start(d+1); reader uses off[d-1]..off[d].
__global__ void k_fill(const int* __restrict__ src, const int* __restrict__ dst,
                       int* __restrict__ off, int* __restrict__ csrc, int E) {
    int i = blockIdx.x * blockDim.x + threadIdx.x;
    if (i < E) {
        int slot = atomicAdd(&off[dst[i]], 1);
        csrc[slot] = src[i];
    }
}

// ---------------- GEMM1: h1 = (x*nO) @ W1, 128->64 ----------------
__global__ void k_gemm1(const float* __restrict__ x, const float* __restrict__ W1,
                        const float* __restrict__ nO, float* __restrict__ h1, int n) {
    __shared__ float sW[128 * 64];
    for (int i = threadIdx.x; i < 128 * 64; i += blockDim.x) sW[i] = W1[i];
    __syncthreads();
    int col = threadIdx.x & 63;
    int row = blockIdx.x * 16 + (threadIdx.x >> 6);
    if (row >= n) return;
    const float4* xr4 = (const float4*)(x + (size_t)row * 128);
    float acc = 0.f;
#pragma unroll
    for (int k4 = 0; k4 < 32; k4++) {
        float4 xv = xr4[k4];
        int kb = k4 * 4;
        acc = fmaf(xv.x, sW[(kb + 0) * 64 + col], acc);
        acc = fmaf(xv.y, sW[(kb + 1) * 64 + col], acc);
        acc = fmaf(xv.z, sW[(kb + 2) * 64 + col], acc);
        acc = fmaf(xv.w, sW[(kb + 3) * 64 + col], acc);
    }
    h1[(size_t)row * 64 + col] = acc * nO[row];
}

// ---------------- agg1: one wave per node, 64 cols ----------------
// x2[node] = relu(sum_{e in in(node)} h1[src_e] * nI[node] + b1)
__global__ void k_agg64(const float* __restrict__ h, const int* __restrict__ csrc,
                        const int* __restrict__ off, const float* __restrict__ nI,
                        const float* __restrict__ b1, float* __restrict__ x2, int n) {
    int node = blockIdx.x * 4 + (threadIdx.x >> 6);
    int lane = threadIdx.x & 63;
    if (node >= n) return;
    int s0 = node ? off[node - 1] : 0;
    int s1 = off[node];
    float a0 = 0.f, a1 = 0.f, a2 = 0.f, a3 = 0.f;
    int e = s0;
    for (; e + 3 < s1; e += 4) {
        int i0 = csrc[e], i1 = csrc[e + 1], i2 = csrc[e + 2], i3 = csrc[e + 3];
        a0 += h[(size_t)i0 * 64 + lane];
        a1 += h[(size_t)i1 * 64 + lane];
        a2 += h[(size_t)i2 * 64 + lane];
        a3 += h[(size_t)i3 * 64 + lane];
    }
    for (; e < s1; e++) a0 += h[(size_t)csrc[e] * 64 + lane];
    float acc = (a0 + a1) + (a2 + a3);
    x2[(size_t)node * 64 + lane] = fmaxf(fmaf(acc, nI[node], b1[lane]), 0.f);
}

// ---------------- GEMM2: h2 = (x2*nO) @ W2, 64->32 ----------------
__global__ void k_gemm2(const float* __restrict__ x2, const float* __restrict__ W2,
                        const float* __restrict__ nO, float* __restrict__ h2, int n) {
    __shared__ float sW[64 * 32];
    for (int i = threadIdx.x; i < 64 * 32; i += blockDim.x) sW[i] = W2[i];
    __syncthreads();
    int col = threadIdx.x & 31;
    int row = blockIdx.x * 32 + (threadIdx.x >> 5);
    if (row >= n) return;
    const float* ar = x2 + (size_t)row * 64;
    float acc = 0.f;
#pragma unroll
    for (int c = 0; c < 64; c++) acc = fmaf(ar[c], sW[c * 32 + col], acc);
    h2[(size_t)row * 32 + col] = acc * nO[row];
}

// ---------------- agg2: one wave per node, 32 cols, 2 edges/iter ----------------
// out[node] = sum h2[src_e] * nI[node] + b2
__global__ void k_agg32(const float* __restrict__ h, const int* __restrict__ csrc,
                        const int* __restrict__ off, const float* __restrict__ nI,
                        const float* __restrict__ b2, float* __restrict__ out, int n) {
    int node = blockIdx.x * 4 + (threadIdx.x >> 6);
    int lane = threadIdx.x & 63;
    int half = lane >> 5, col = lane & 31;
    if (node >= n) return;
    int s0 = node ? off[node - 1] : 0;
    int s1 = off[node];
    float a0 = 0.f, a1 = 0.f;
    int e = s0 + half;
    for (; e + 2 < s1; e += 4) {          // this half handles e and e+2
        a0 += h[(size_t)csrc[e] * 32 + col];
        a1 += h[(size_t)csrc[e + 2] * 32 + col];
    }
    for (; e < s1; e += 2) a0 += h[(size_t)csrc[e] * 32 + col];
    float acc = a0 + a1;
    acc += __shfl(acc, lane ^ 32, 64);    // combine the two halves
    if (half == 0) out[(size_t)node * 32 + col] = fmaf(acc, nI[node], b2[col]);
}

extern "C" void kernel_launch(void* const* d_in, const int* in_sizes, int n_in,
                              void* d_out, int out_size, void* d_ws, size_t ws_size,
                              hipStream_t stream) {
    const float* x   = (const float*)d_in[0];  // [N,128]
    const int*   src = (const int*)d_in[1];    // [E]
    const int*   dst = (const int*)d_in[2];    // [E]
    const float* W1  = (const float*)d_in[3];  // [128,64]
    const float* b1  = (const float*)d_in[4];  // [64]
    const float* W2  = (const float*)d_in[5];  // [64,32]
    const float* b2  = (const float*)d_in[6];  // [32]
    float* out = (float*)d_out;                // [N,32]

    const int N = in_sizes[0] / 128;           // 100000
    const int E = in_sizes[1];                 // 1600000
    const int B = (N + 1023) / 1024;           // scan chunks (98)

    // workspace layout (4-byte units)
    char* wsb = (char*)d_ws;
    int*   dO      = (int*)wsb;                          wsb += (size_t)N * 4;
    int*   dI      = (int*)wsb;                          wsb += (size_t)N * 4;
    float* nO      = (float*)wsb;                        wsb += (size_t)N * 4;
    float* nI      = (float*)wsb;                        wsb += (size_t)N * 4;
    int*   off     = (int*)wsb;                          wsb += (size_t)N * 4;
    int*   partial = (int*)wsb;                          wsb += (size_t)1024 * 4;
    int*   csrc    = (int*)wsb;                          wsb += (size_t)E * 4;
    float* h1      = (float*)wsb;                        wsb += (size_t)N * 64 * 4;
    float* x2      = (float*)wsb;                        wsb += (size_t)N * 64 * 4;
    float* h2      = h1;  // h1 dead after k_agg64

    // zero only the degree counters (everything else is fully overwritten)
    hipMemsetAsync(dO, 0, (size_t)N * sizeof(int), stream);
    hipMemsetAsync(dI, 0, (size_t)N * sizeof(int), stream);

    // degrees + norms
    k_degree<<<(E + 255) / 256, 256, 0, stream>>>(src, dst, dO, dI, E);
    k_norm<<<(N + 255) / 256, 256, 0, stream>>>(dO, dI, nO, nI, N);

    // CSR build: exclusive scan of dI -> off, then fill (off becomes "ends")
    k_scan_a<<<B, 1024, 0, stream>>>(dI, off, partial, N);
    k_scan_b<<<1, 1024, 0, stream>>>(partial, B);
    k_scan_c<<<B, 1024, 0, stream>>>(off, partial, N);
    k_fill<<<(E + 255) / 256, 256, 0, stream>>>(src, dst, off, csrc, E);

    // layer 1: GEMM then gather-aggregate (relu+b1+in_norm fused)
    k_gemm1<<<(N + 15) / 16, 1024, 0, stream>>>(x, W1, nO, h1, N);
    k_agg64<<<(N + 3) / 4, 256, 0, stream>>>(h1, csrc, off, nI, b1, x2, N);

    // layer 2: GEMM (out_norm fused) then gather-aggregate (b2+in_norm fused)
    k_gemm2<<<(N + 31) / 32, 1024, 0, stream>>>(x2, W2, nO, h2, N);
    k_agg32<<<(N + 3) / 4, 256, 0, stream>>>(h2, csrc, off, nI, b2, out, N);
}

// Round 4
// 520.288 us; speedup vs baseline: 1.8240x; 1.2161x over previous
//
#include <hip/hip_runtime.h>
#include <hip/hip_bf16.h>

// GNN: 2-layer GraphConv (DGL norm='both'), N=100000, E=1600000.
// Round 4: register-tiled GEMMs (4x4 outputs/thread, b128 LDS reads,
// conflict-free layouts). CSR gather aggregation kept (round-3 win).

// ---------------- degree count (int atomics) ----------------
__global__ void k_degree(const int* __restrict__ src, const int* __restrict__ dst,
                         int* __restrict__ dO, int* __restrict__ dI, int E) {
    int i = blockIdx.x * blockDim.x + threadIdx.x;
    if (i < E) {
        atomicAdd(&dO[src[i]], 1);
        atomicAdd(&dI[dst[i]], 1);
    }
}

__global__ void k_norm(const int* __restrict__ dO, const int* __restrict__ dI,
                       float* __restrict__ nO, float* __restrict__ nI, int n) {
    int i = blockIdx.x * blockDim.x + threadIdx.x;
    if (i < n) {
        nO[i] = rsqrtf(fmaxf((float)dO[i], 1.0f));
        nI[i] = rsqrtf(fmaxf((float)dI[i], 1.0f));
    }
}

// ---------------- hierarchical exclusive scan of dI -> off ----------------
__global__ void k_scan_a(const int* __restrict__ deg, int* __restrict__ off,
                         int* __restrict__ partial, int n) {
    __shared__ int tmp[1024];
    int t = threadIdx.x;
    int i = blockIdx.x * 1024 + t;
    int v = (i < n) ? deg[i] : 0;
    tmp[t] = v;
    __syncthreads();
    for (int o = 1; o < 1024; o <<= 1) {
        int u = (t >= o) ? tmp[t - o] : 0;
        __syncthreads();
        tmp[t] += u;
        __syncthreads();
    }
    if (i < n) off[i] = tmp[t] - v;          // exclusive
    if (t == 1023) partial[blockIdx.x] = tmp[t];
}

__global__ void k_scan_b(int* __restrict__ partial, int B) {
    __shared__ int s[1024];
    int t = threadIdx.x;
    for (int i = t; i < B; i += blockDim.x) s[i] = partial[i];
    __syncthreads();
    if (t == 0) {
        int acc = 0;
        for (int i = 0; i < B; i++) { int v = s[i]; s[i] = acc; acc += v; }
    }
    __syncthreads();
    for (int i = t; i < B; i += blockDim.x) partial[i] = s[i];
}

__global__ void k_scan_c(int* __restrict__ off, const int* __restrict__ partial, int n) {
    int i = blockIdx.x * 1024 + threadIdx.x;
    if (i < n) off[i] += partial[blockIdx.x];
}

// ---------------- CSR fill ----------------
__global__ void k_fill(const int* __restrict__ src, const int* __restrict__ dst,
                       int* __restrict__ off, int* __restrict__ csrc, int E) {
    int i = blockIdx.x * blockDim.x + threadIdx.x;
    if (i < E) {
        int slot = atomicAdd(&off[dst[i]], 1);
        csrc[slot] = src[i];
    }
}

// ---------------- GEMM1: h1 = (x*nO) @ W1, 128->64, 4x4 register tile ----------
// block 256 thr = 4 waves; block tile 64 rows x 64 cols; K=128.
// Thread (wave wv, lane): rows {rg,rg+16,rg+32,rg+48}, cols c0..c0+3 (c0=wv*16+cg*4).
// sX[row][k] stride 132 (pad, 16B aligned): x-read bank = 4*rg%32 -> 2-way (free).
// sW[k][col] natural: w-read is 16-lane broadcast (free).
__global__ __launch_bounds__(256) void k_gemm1(const float* __restrict__ x,
                        const float* __restrict__ W1, const float* __restrict__ nO,
                        float* __restrict__ h1, int n) {
    __shared__ float sX[64 * 132];
    __shared__ float sW[128 * 64];
    const int t = threadIdx.x;
    {
        const float4* W4 = (const float4*)W1;
        float4* sW4 = (float4*)sW;
#pragma unroll
        for (int i = 0; i < 8; i++) sW4[t + 256 * i] = W4[t + 256 * i];
    }
    const int rowbase = blockIdx.x * 64;
    {
        const float4* x4 = (const float4*)x;
        float4* sX4 = (float4*)sX;
#pragma unroll
        for (int i = 0; i < 8; i++) {
            int f = t + 256 * i;
            int row = f >> 5, kc = f & 31;
            int grow = rowbase + row;
            float4 v = make_float4(0.f, 0.f, 0.f, 0.f);
            if (grow < n) v = x4[(size_t)grow * 32 + kc];
            sX4[row * 33 + kc] = v;      // stride 132 floats = 33 float4
        }
    }
    __syncthreads();
    const int lane = t & 63, wv = t >> 6;
    const int rg = lane >> 2, cg = lane & 3;
    const int c0 = wv * 16 + cg * 4;
    float acc[4][4] = {};
    for (int kk = 0; kk < 128; kk += 4) {
        float xr[4][4], wr[4][4];
#pragma unroll
        for (int i = 0; i < 4; i++)
            *(float4*)xr[i] = *(const float4*)&sX[(rg + 16 * i) * 132 + kk];
#pragma unroll
        for (int j = 0; j < 4; j++)
            *(float4*)wr[j] = *(const float4*)&sW[(kk + j) * 64 + c0];
#pragma unroll
        for (int j = 0; j < 4; j++)
#pragma unroll
            for (int i = 0; i < 4; i++)
#pragma unroll
                for (int c = 0; c < 4; c++)
                    acc[i][c] = fmaf(xr[i][j], wr[j][c], acc[i][c]);
    }
#pragma unroll
    for (int i = 0; i < 4; i++) {
        int grow = rowbase + rg + 16 * i;
        if (grow < n) {
            float nf = nO[grow];
            float4 o = make_float4(acc[i][0] * nf, acc[i][1] * nf,
                                   acc[i][2] * nf, acc[i][3] * nf);
            *(float4*)&h1[(size_t)grow * 64 + c0] = o;
        }
    }
}

// ---------------- agg1: one wave per node, 64 cols, unroll 8 ----------------
__global__ void k_agg64(const float* __restrict__ h, const int* __restrict__ csrc,
                        const int* __restrict__ off, const float* __restrict__ nI,
                        const float* __restrict__ b1, float* __restrict__ x2, int n) {
    int node = blockIdx.x * 4 + (threadIdx.x >> 6);
    int lane = threadIdx.x & 63;
    if (node >= n) return;
    int s0 = node ? off[node - 1] : 0;
    int s1 = off[node];
    float a0 = 0.f, a1 = 0.f, a2 = 0.f, a3 = 0.f;
    float a4 = 0.f, a5 = 0.f, a6 = 0.f, a7 = 0.f;
    int e = s0;
    for (; e + 7 < s1; e += 8) {
        int i0 = csrc[e], i1 = csrc[e + 1], i2 = csrc[e + 2], i3 = csrc[e + 3];
        int i4 = csrc[e + 4], i5 = csrc[e + 5], i6 = csrc[e + 6], i7 = csrc[e + 7];
        a0 += h[(size_t)i0 * 64 + lane];
        a1 += h[(size_t)i1 * 64 + lane];
        a2 += h[(size_t)i2 * 64 + lane];
        a3 += h[(size_t)i3 * 64 + lane];
        a4 += h[(size_t)i4 * 64 + lane];
        a5 += h[(size_t)i5 * 64 + lane];
        a6 += h[(size_t)i6 * 64 + lane];
        a7 += h[(size_t)i7 * 64 + lane];
    }
    for (; e < s1; e++) a0 += h[(size_t)csrc[e] * 64 + lane];
    float acc = ((a0 + a1) + (a2 + a3)) + ((a4 + a5) + (a6 + a7));
    x2[(size_t)node * 64 + lane] = fmaxf(fmaf(acc, nI[node], b1[lane]), 0.f);
}

// ---------------- GEMM2: h2 = (x2*nO) @ W2, 64->32, 4x4 register tile --------
// block 256 = 4 waves; block tile 128 rows x 32 cols; K=64.
// wave: whalf=wv>>1 (64-row half), chalf=wv&1 (16-col half).
// sX2[row][k] stride 68 (pad): x-read bank = 4*rg%32 -> 2-way free.
__global__ __launch_bounds__(256) void k_gemm2(const float* __restrict__ x2,
                        const float* __restrict__ W2, const float* __restrict__ nO,
                        float* __restrict__ h2, int n) {
    __shared__ float sX[128 * 68];
    __shared__ float sW[64 * 32];
    const int t = threadIdx.x;
    {
        const float4* W4 = (const float4*)W2;
        float4* sW4 = (float4*)sW;
#pragma unroll
        for (int i = 0; i < 2; i++) sW4[t + 256 * i] = W4[t + 256 * i];
    }
    const int rowbase = blockIdx.x * 128;
    {
        const float4* x4 = (const float4*)x2;
        float4* sX4 = (float4*)sX;
#pragma unroll
        for (int i = 0; i < 8; i++) {
            int f = t + 256 * i;
            int row = f >> 4, kc = f & 15;
            int grow = rowbase + row;
            float4 v = make_float4(0.f, 0.f, 0.f, 0.f);
            if (grow < n) v = x4[(size_t)grow * 16 + kc];
            sX4[row * 17 + kc] = v;      // stride 68 floats = 17 float4
        }
    }
    __syncthreads();
    const int lane = t & 63, wv = t >> 6;
    const int whalf = wv >> 1, chalf = wv & 1;
    const int rg = lane >> 2, cg = lane & 3;
    const int c0 = chalf * 16 + cg * 4;
    const int rloc = whalf * 64 + rg;    // + 16*i
    float acc[4][4] = {};
    for (int kk = 0; kk < 64; kk += 4) {
        float xr[4][4], wr[4][4];
#pragma unroll
        for (int i = 0; i < 4; i++)
            *(float4*)xr[i] = *(const float4*)&sX[(rloc + 16 * i) * 68 + kk];
#pragma unroll
        for (int j = 0; j < 4; j++)
            *(float4*)wr[j] = *(const float4*)&sW[(kk + j) * 32 + c0];
#pragma unroll
        for (int j = 0; j < 4; j++)
#pragma unroll
            for (int i = 0; i < 4; i++)
#pragma unroll
                for (int c = 0; c < 4; c++)
                    acc[i][c] = fmaf(xr[i][j], wr[j][c], acc[i][c]);
    }
#pragma unroll
    for (int i = 0; i < 4; i++) {
        int grow = rowbase + rloc + 16 * i;
        if (grow < n) {
            float nf = nO[grow];
            float4 o = make_float4(acc[i][0] * nf, acc[i][1] * nf,
                                   acc[i][2] * nf, acc[i][3] * nf);
            *(float4*)&h2[(size_t)grow * 32 + c0] = o;
        }
    }
}

// ---------------- agg2: one wave per node, 32 cols ----------------
__global__ void k_agg32(const float* __restrict__ h, const int* __restrict__ csrc,
                        const int* __restrict__ off, const float* __restrict__ nI,
                        const float* __restrict__ b2, float* __restrict__ out, int n) {
    int node = blockIdx.x * 4 + (threadIdx.x >> 6);
    int lane = threadIdx.x & 63;
    int half = lane >> 5, col = lane & 31;
    if (node >= n) return;
    int s0 = node ? off[node - 1] : 0;
    int s1 = off[node];
    float a0 = 0.f, a1 = 0.f, a2 = 0.f, a3 = 0.f;
    int e = s0 + half;
    for (; e + 6 < s1; e += 8) {         // this half handles e, e+2, e+4, e+6
        a0 += h[(size_t)csrc[e] * 32 + col];
        a1 += h[(size_t)csrc[e + 2] * 32 + col];
        a2 += h[(size_t)csrc[e + 4] * 32 + col];
        a3 += h[(size_t)csrc[e + 6] * 32 + col];
    }
    for (; e < s1; e += 2) a0 += h[(size_t)csrc[e] * 32 + col];
    float acc = (a0 + a1) + (a2 + a3);
    acc += __shfl(acc, lane ^ 32, 64);
    if (half == 0) out[(size_t)node * 32 + col] = fmaf(acc, nI[node], b2[col]);
}

extern "C" void kernel_launch(void* const* d_in, const int* in_sizes, int n_in,
                              void* d_out, int out_size, void* d_ws, size_t ws_size,
                              hipStream_t stream) {
    const float* x   = (const float*)d_in[0];  // [N,128]
    const int*   src = (const int*)d_in[1];    // [E]
    const int*   dst = (const int*)d_in[2];    // [E]
    const float* W1  = (const float*)d_in[3];  // [128,64]
    const float* b1  = (const float*)d_in[4];  // [64]
    const float* W2  = (const float*)d_in[5];  // [64,32]
    const float* b2  = (const float*)d_in[6];  // [32]
    float* out = (float*)d_out;                // [N,32]

    const int N = in_sizes[0] / 128;           // 100000
    const int E = in_sizes[1];                 // 1600000
    const int B = (N + 1023) / 1024;           // scan chunks (98)

    char* wsb = (char*)d_ws;
    int*   dO      = (int*)wsb;                          wsb += (size_t)N * 4;
    int*   dI      = (int*)wsb;                          wsb += (size_t)N * 4;
    float* nO      = (float*)wsb;                        wsb += (size_t)N * 4;
    float* nI      = (float*)wsb;                        wsb += (size_t)N * 4;
    int*   off     = (int*)wsb;                          wsb += (size_t)N * 4;
    int*   partial = (int*)wsb;                          wsb += (size_t)1024 * 4;
    int*   csrc    = (int*)wsb;                          wsb += (size_t)E * 4;
    float* h1      = (float*)wsb;                        wsb += (size_t)N * 64 * 4;
    float* x2      = (float*)wsb;                        wsb += (size_t)N * 64 * 4;
    float* h2      = h1;  // h1 dead after k_agg64

    hipMemsetAsync(dO, 0, (size_t)N * sizeof(int), stream);
    hipMemsetAsync(dI, 0, (size_t)N * sizeof(int), stream);

    k_degree<<<(E + 255) / 256, 256, 0, stream>>>(src, dst, dO, dI, E);
    k_norm<<<(N + 255) / 256, 256, 0, stream>>>(dO, dI, nO, nI, N);

    k_scan_a<<<B, 1024, 0, stream>>>(dI, off, partial, N);
    k_scan_b<<<1, 1024, 0, stream>>>(partial, B);
    k_scan_c<<<B, 1024, 0, stream>>>(off, partial, N);
    k_fill<<<(E + 255) / 256, 256, 0, stream>>>(src, dst, off, csrc, E);

    k_gemm1<<<(N + 63) / 64, 256, 0, stream>>>(x, W1, nO, h1, N);
    k_agg64<<<(N + 3) / 4, 256, 0, stream>>>(h1, csrc, off, nI, b1, x2, N);

    k_gemm2<<<(N + 127) / 128, 256, 0, stream>>>(x2, W2, nO, h2, N);
    k_agg32<<<(N + 3) / 4, 256, 0, stream>>>(h2, csrc, off, nI, b2, out, N);
}